// Round 3
// baseline (702.107 us; speedup 1.0000x reference)
//
#include <hip/hip_runtime.h>

#define B_ 8
#define C_ 64
#define N_ 512
#define T_ 288
#define K_ 32

typedef __bf16 bf16;
typedef __attribute__((ext_vector_type(4))) __bf16 bf16x4;
typedef __attribute__((ext_vector_type(8))) __bf16 bf16x8;
typedef __attribute__((ext_vector_type(4))) float f32x4;

// Load input element i as float, branching (wave-uniformly) on runtime dtype flag.
__device__ __forceinline__ float ldin(const void* p, int f32, size_t i) {
    if (f32) return ((const float*)p)[i];
    return (float)((const bf16*)p)[i];
}

// ---------------- K-1: detect input dtype ----------------
// x ~ N(0,1). Read first 4096 elements AS bf16: if buffer is really fp32,
// half of those are random mantissa bits -> some |v| astronomically large.
__global__ void k_detect(const void* __restrict__ x, int* __restrict__ flag) {
    __shared__ float sm[256];
    const bf16* xb = (const bf16*)x;
    float m = 0.f;
    for (int i = threadIdx.x; i < 4096; i += 256) {
        float a = fabsf((float)xb[i]);
        if (!(a <= 1000.f)) a = 1e30f;   // catches NaN too
        m = fmaxf(m, a);
    }
    sm[threadIdx.x] = m;
    __syncthreads();
    if (threadIdx.x == 0) {
        float mm = 0.f;
        for (int i = 0; i < 256; ++i) mm = fmaxf(mm, sm[i]);
        *flag = (mm > 1000.f) ? 1 : 0;   // 1 = fp32 buffers, 0 = bf16 buffers
    }
}

// ---------------- K0: convert HEs -> hesb [N][K], hest [K][N]; em -> emb ----
__global__ void k_prep(const void* __restrict__ hes, const void* __restrict__ em,
                       const int* __restrict__ flag,
                       bf16* __restrict__ hesb, bf16* __restrict__ hest,
                       bf16* __restrict__ emb) {
    const int f32 = *flag;
    int idx = blockIdx.x * 256 + threadIdx.x;
    if (idx < N_ * K_) {
        float v = ldin(hes, f32, idx);
        hesb[idx] = (bf16)v;
        int n = idx >> 5, k = idx & 31;
        hest[k * N_ + n] = (bf16)v;
    }
    if (idx < K_ * K_) emb[idx] = (bf16)ldin(em, f32, idx);
}

// ---------------- K1: HF = HEs^T @ X_c ; HO = relu(EM@HF)+HF -------------
// grid: (9 t-tiles of 32, C, B), block: 64 (one wave); mfma_f32_16x16x32_bf16 only.
__global__ __launch_bounds__(64) void k_hyper(const void* __restrict__ x,
                                              const int* __restrict__ flag,
                                              const bf16* __restrict__ hest,
                                              const bf16* __restrict__ emb,
                                              bf16* __restrict__ ho) {
    const int f32 = *flag;
    const int tile = blockIdx.x, c = blockIdx.y, b = blockIdx.z;
    const int lane = threadIdx.x;
    const int col  = lane & 15;   // A row (m) / B col / C-D col
    const int q    = lane >> 4;   // quad: ctr sub-chunk of 8
    const int t0   = tile * 32;
    const size_t xbase = ((size_t)(b * C_ + c)) * N_ * T_;

    // HF[k][t] = sum_n HEsT[k][n] * X[n][t]; 2x2 tiles of 16x16, 16 ctr-steps of 32
    f32x4 acc[2][2] = {};
    for (int step = 0; step < 16; ++step) {
        const int nb = step * 32;
        bf16x8 a0 = *(const bf16x8*)(hest + (size_t)(col) * N_ + nb + 8 * q);
        bf16x8 a1 = *(const bf16x8*)(hest + (size_t)(16 + col) * N_ + nb + 8 * q);
        bf16x8 b0, b1;
        const size_t xq = xbase + (size_t)(nb + 8 * q) * T_ + t0;
        #pragma unroll
        for (int j = 0; j < 8; ++j) {
            b0[j] = (bf16)ldin(x, f32, xq + (size_t)j * T_ + col);
            b1[j] = (bf16)ldin(x, f32, xq + (size_t)j * T_ + 16 + col);
        }
        acc[0][0] = __builtin_amdgcn_mfma_f32_16x16x32_bf16(a0, b0, acc[0][0], 0, 0, 0);
        acc[0][1] = __builtin_amdgcn_mfma_f32_16x16x32_bf16(a0, b1, acc[0][1], 0, 0, 0);
        acc[1][0] = __builtin_amdgcn_mfma_f32_16x16x32_bf16(a1, b0, acc[1][0], 0, 0, 0);
        acc[1][1] = __builtin_amdgcn_mfma_f32_16x16x32_bf16(a1, b1, acc[1][1], 0, 0, 0);
    }

    // Stage HF to LDS (C/D layout: row=4q+r, col=col within each 16x16 tile)
    __shared__ float hf[K_][33];   // [k][t]
    #pragma unroll
    for (int mt = 0; mt < 2; ++mt)
        #pragma unroll
        for (int tt = 0; tt < 2; ++tt)
            #pragma unroll
            for (int r = 0; r < 4; ++r)
                hf[16 * mt + 4 * q + r][16 * tt + col] = acc[mt][tt][r];
    __syncthreads();

    // HM = EM @ HF: one K=32 MFMA per (mt, tt)
    f32x4 acc2[2][2];
    #pragma unroll
    for (int mt = 0; mt < 2; ++mt) {
        bf16x8 a = *(const bf16x8*)(emb + (size_t)(16 * mt + col) * K_ + 8 * q);
        #pragma unroll
        for (int tt = 0; tt < 2; ++tt) {
            bf16x8 bb;
            #pragma unroll
            for (int jj = 0; jj < 8; ++jj)
                bb[jj] = (bf16)hf[8 * q + jj][16 * tt + col];
            f32x4 zero = {};
            acc2[mt][tt] = __builtin_amdgcn_mfma_f32_16x16x32_bf16(a, bb, zero, 0, 0, 0);
        }
    }

    // HO = relu(HM) + HF, store bf16 as [b][c][t][k] (k innermost)
    #pragma unroll
    for (int mt = 0; mt < 2; ++mt)
        #pragma unroll
        for (int tt = 0; tt < 2; ++tt) {
            bf16x4 v;
            #pragma unroll
            for (int r = 0; r < 4; ++r) {
                float hv = acc2[mt][tt][r];
                hv = hv > 0.f ? hv : 0.f;
                hv += acc[mt][tt][r];
                v[r] = (bf16)hv;   // k = 16*mt + 4*q + r
            }
            *(bf16x4*)(ho + (((size_t)(b * C_ + c)) * T_ + t0 + 16 * tt + col) * K_
                          + 16 * mt + 4 * q) = v;
        }
}

// ---------------- K2: y = relu(HEs @ HO); z = y + x; LN over C; store ----
// grid: (18 t-tiles, 32 n-tiles, B), block: 256 (4 waves x 16 c-planes)
__global__ __launch_bounds__(256) void k_scatter_ln(const void* __restrict__ x,
                                                    const int* __restrict__ flag,
                                                    const bf16* __restrict__ hesb,
                                                    const bf16* __restrict__ ho,
                                                    void* __restrict__ outp) {
    const int f32 = *flag;
    const int t0 = blockIdx.x * 16;
    const int n0 = blockIdx.y * 16;
    const int b  = blockIdx.z;
    const int tid  = threadIdx.x;
    const int w    = tid >> 6;
    const int lane = tid & 63;
    const int col  = lane & 15;   // t within tile
    const int q    = lane >> 4;   // quad

    // A-frag: HEs[n0+col][8q+j], contiguous 16B
    bf16x8 a = *(const bf16x8*)(hesb + (size_t)(n0 + col) * K_ + 8 * q);

    f32x4 z[16];
    const bf16* hob = ho + (((size_t)(b * C_)) * T_ + t0 + col) * K_ + 8 * q;
    #pragma unroll
    for (int i = 0; i < 16; ++i) {
        int c = w * 16 + i;
        bf16x8 bb = *(const bf16x8*)(hob + (size_t)c * T_ * K_);
        f32x4 zero = {};
        z[i] = __builtin_amdgcn_mfma_f32_16x16x32_bf16(a, bb, zero, 0, 0, 0);
    }

    // relu + residual, accumulate LN stats over this wave's 16 c's
    float s1[4] = {0.f, 0.f, 0.f, 0.f}, s2[4] = {0.f, 0.f, 0.f, 0.f};
    const size_t xb = ((size_t)b * C_) * (size_t)N_ * T_;
    #pragma unroll
    for (int i = 0; i < 16; ++i) {
        int c = w * 16 + i;
        #pragma unroll
        for (int r = 0; r < 4; ++r) {
            int row = q * 4 + r;
            float zz = z[i][r];
            zz = zz > 0.f ? zz : 0.f;
            zz += ldin(x, f32, xb + ((size_t)c * N_ + n0 + row) * T_ + t0 + col);
            z[i][r] = zz;
            s1[r] += zz;
            s2[r] += zz * zz;
        }
    }

    __shared__ float sh1[4][16][17];
    __shared__ float sh2[4][16][17];
    #pragma unroll
    for (int r = 0; r < 4; ++r) {
        sh1[w][q * 4 + r][col] = s1[r];
        sh2[w][q * 4 + r][col] = s2[r];
    }
    __syncthreads();

    {   // one thread per (n-row, t-col): reduce across waves -> mu, rstd
        int rr = tid >> 4, cc = tid & 15;
        float S1 = sh1[0][rr][cc] + sh1[1][rr][cc] + sh1[2][rr][cc] + sh1[3][rr][cc];
        float S2 = sh2[0][rr][cc] + sh2[1][rr][cc] + sh2[2][rr][cc] + sh2[3][rr][cc];
        float mu  = S1 * (1.f / 64.f);
        float var = S2 * (1.f / 64.f) - mu * mu;
        float rs  = rsqrtf(var + 1e-5f);
        sh1[0][rr][cc] = mu;
        sh2[0][rr][cc] = rs;
    }
    __syncthreads();

    float mu_r[4], rs_r[4];
    #pragma unroll
    for (int r = 0; r < 4; ++r) {
        mu_r[r] = sh1[0][q * 4 + r][col];
        rs_r[r] = sh2[0][q * 4 + r][col];
    }
    #pragma unroll
    for (int i = 0; i < 16; ++i) {
        int c = w * 16 + i;
        size_t ob = ((size_t)(b * C_ + c) * N_ + n0) * T_ + t0 + col;
        #pragma unroll
        for (int r = 0; r < 4; ++r) {
            float v = (z[i][r] - mu_r[r]) * rs_r[r];
            size_t idx = ob + (size_t)(q * 4 + r) * T_;
            if (f32) ((float*)outp)[idx] = v;
            else     ((bf16*)outp)[idx] = (bf16)v;
        }
    }
}

extern "C" void kernel_launch(void* const* d_in, const int* in_sizes, int n_in,
                              void* d_out, int out_size, void* d_ws, size_t ws_size,
                              hipStream_t stream) {
    const void* x   = d_in[0];
    const void* hes = d_in[1];
    const void* em  = d_in[2];

    char* ws = (char*)d_ws;
    int*  flag = (int*)ws;                        // 4 B (+pad)
    bf16* hesb = (bf16*)(ws + 64);                // 32 KB  [N][K]
    bf16* hest = hesb + (size_t)N_ * K_;          // 32 KB  [K][N]
    bf16* emb  = hest + (size_t)K_ * N_;          // 2 KB   [K][K]
    bf16* ho   = emb  + (size_t)K_ * K_;          // 9.44 MB [B][C][T][K]

    k_detect<<<1, 256, 0, stream>>>(x, flag);
    k_prep<<<dim3((N_ * K_ + 255) / 256), 256, 0, stream>>>(hes, em, flag, hesb, hest, emb);
    k_hyper<<<dim3(T_ / 32, C_, B_), 64, 0, stream>>>(x, flag, hest, emb, ho);
    k_scatter_ln<<<dim3(T_ / 16, N_ / 16, B_), 256, 0, stream>>>(x, flag, hesb, ho, d_out);
}